// Round 1
// baseline (956.766 us; speedup 1.0000x reference)
//
#include <hip/hip_runtime.h>
#include <cstdint>
#include <cstddef>

#define NEG_SLOPE 0.2f

__device__ __forceinline__ float leakyf(float x) { return x > 0.f ? x : NEG_SLOPE * x; }
__device__ __forceinline__ float fast_tanh(float x) {
    float e = __expf(2.f * x);
    return 1.f - 2.f / (e + 1.f);
}

// ---------------- projection (x@W+b) + per-head attention dots ----------------
// block 256 = 8 row-groups x 32 col-threads; 32 rows/block, thread = 4 rows x 4 cols
__global__ __launch_bounds__(256) void proj_kernel(
    const float* __restrict__ x, const float* __restrict__ W, const float* __restrict__ bias,
    float* __restrict__ hout, int N,
    const float* __restrict__ att0, float* __restrict__ e0,
    const float* __restrict__ att1, float* __restrict__ e1,
    const float* __restrict__ att2, float* __restrict__ e2)
{
    __shared__ float lds[32 * 128];
    const int t = threadIdx.x;
    const int row0 = blockIdx.x * 32;
    #pragma unroll
    for (int p = 0; p < 4; ++p) {
        int idx = t + 256 * p;
        int r = idx >> 5;
        int c4 = idx & 31;
        float4 v = make_float4(0.f, 0.f, 0.f, 0.f);
        if (row0 + r < N) v = *(const float4*)(x + (size_t)(row0 + r) * 128 + c4 * 4);
        *(float4*)(lds + r * 128 + c4 * 4) = v;
    }
    __syncthreads();
    const int rg = t >> 5, ct = t & 31;
    float acc[4][4];
    #pragma unroll
    for (int rr = 0; rr < 4; ++rr)
        #pragma unroll
        for (int c = 0; c < 4; ++c) acc[rr][c] = bias[ct + 32 * c];
    for (int i = 0; i < 128; i += 4) {
        float4 xv[4];
        #pragma unroll
        for (int rr = 0; rr < 4; ++rr) xv[rr] = *(const float4*)(lds + (rg + 8 * rr) * 128 + i);
        #pragma unroll
        for (int qq = 0; qq < 4; ++qq) {
            float wv[4];
            #pragma unroll
            for (int c = 0; c < 4; ++c) wv[c] = W[(size_t)(i + qq) * 128 + ct + 32 * c];
            #pragma unroll
            for (int rr = 0; rr < 4; ++rr) {
                float xs = ((const float*)&xv[rr])[qq];
                #pragma unroll
                for (int c = 0; c < 4; ++c) acc[rr][c] = fmaf(xs, wv[c], acc[rr][c]);
            }
        }
    }
    __syncthreads();  // done reading x tile
    #pragma unroll
    for (int rr = 0; rr < 4; ++rr) {
        int r = rg + 8 * rr;
        int grow = row0 + r;
        #pragma unroll
        for (int c = 0; c < 4; ++c) {
            lds[r * 128 + ct + 32 * c] = acc[rr][c];
            if (grow < N) hout[(size_t)grow * 128 + ct + 32 * c] = acc[rr][c];
        }
    }
    __syncthreads();
    {
        // 256 tasks: 32 rows x 8 heads
        int r = t >> 3, h = t & 7;
        int grow = row0 + r;
        if (grow < N) {
            float s0 = 0.f, s1 = 0.f, s2 = 0.f;
            #pragma unroll
            for (int d = 0; d < 16; ++d) {
                float hv = lds[r * 128 + h * 16 + d];
                if (att0) s0 = fmaf(hv, att0[h * 16 + d], s0);
                if (att1) s1 = fmaf(hv, att1[h * 16 + d], s1);
                if (att2) s2 = fmaf(hv, att2[h * 16 + d], s2);
            }
            if (e0) e0[(size_t)grow * 8 + h] = s0;
            if (e1) e1[(size_t)grow * 8 + h] = s1;
            if (e2) e2[(size_t)grow * 8 + h] = s2;
        }
    }
}

// ---------------- CSR build ----------------
__global__ void hist_kernel(const int* __restrict__ dst, int E, int* cnt) {
    int i = blockIdx.x * 256 + threadIdx.x;
    if (i < E) atomicAdd(&cnt[dst[i]], 1);
}

__global__ void scan_block_reduce(const int* __restrict__ cnt, int N, int* bsum) {
    __shared__ int s[256];
    int t = threadIdx.x;
    int i = blockIdx.x * 256 + t;
    s[t] = (i < N) ? cnt[i] : 0;
    __syncthreads();
    for (int o = 128; o > 0; o >>= 1) {
        if (t < o) s[t] += s[t + o];
        __syncthreads();
    }
    if (t == 0) bsum[blockIdx.x] = s[0];
}

__global__ void scan_bsum(const int* __restrict__ bsum, int nb, int* boff) {
    __shared__ int s[1024];
    int t = threadIdx.x;
    int v = (t < nb) ? bsum[t] : 0;
    s[t] = v;
    __syncthreads();
    for (int o = 1; o < 1024; o <<= 1) {
        int add = (t >= o) ? s[t - o] : 0;
        __syncthreads();
        s[t] += add;
        __syncthreads();
    }
    if (t < nb) boff[t] = s[t] - v;  // exclusive
}

__global__ void scan_final(const int* __restrict__ cnt, int N, const int* __restrict__ boff,
                           int* off, int E) {
    __shared__ int s[256];
    int t = threadIdx.x;
    int i = blockIdx.x * 256 + t;
    int v = (i < N) ? cnt[i] : 0;
    s[t] = v;
    __syncthreads();
    for (int o = 1; o < 256; o <<= 1) {
        int add = (t >= o) ? s[t - o] : 0;
        __syncthreads();
        s[t] += add;
        __syncthreads();
    }
    if (i < N) off[i] = s[t] - v + boff[blockIdx.x];
    if (blockIdx.x == 0 && t == 0) off[N] = E;
}

__global__ void scatter_kernel(const int* __restrict__ dst, int E, int* run, int* eidx) {
    int i = blockIdx.x * 256 + threadIdx.x;
    if (i < E) {
        int p = atomicAdd(&run[dst[i]], 1);
        eidx[p] = i;
    }
}

// ---------------- per-dst-node softmax aggregation (1 wave per node) ----------------
__global__ __launch_bounds__(256) void aggregate_kernel(
    const float* __restrict__ xs,     // [Ns,128] projected src feats
    const float* __restrict__ esrc,   // [Ns,8]
    const float* __restrict__ edst,   // [Nd,8]
    const int* __restrict__ off,      // [Nd+1]
    const int* __restrict__ eidx,     // [E] edge ids bucketed by dst
    const int* __restrict__ srcarr,   // [E] original src array
    float* __restrict__ outp,         // [Nd,128]
    int Nd)
{
    const int lane = threadIdx.x & 63;
    const int n = blockIdx.x * 4 + (threadIdx.x >> 6);
    if (n >= Nd) return;
    const int j0 = lane * 2;
    const int h = lane >> 3;
    const int o0 = off[n], o1 = off[n + 1];
    const int deg = o1 - o0;
    if (deg == 0) {
        *(float2*)(outp + (size_t)n * 128 + j0) = make_float2(0.f, 0.f);
        return;
    }
    float ed[8];
    {
        float4 a = *(const float4*)(edst + (size_t)n * 8);
        float4 b = *(const float4*)(edst + (size_t)n * 8 + 4);
        ed[0] = a.x; ed[1] = a.y; ed[2] = a.z; ed[3] = a.w;
        ed[4] = b.x; ed[5] = b.y; ed[6] = b.z; ed[7] = b.w;
    }
    float m[8];
    #pragma unroll
    for (int hh = 0; hh < 8; ++hh) m[hh] = -1e30f;
    // phase A: per-head max over incoming edges (lane-parallel)
    for (int base = 0; base < deg; base += 64) {
        int ii = base + lane;
        bool act = ii < deg;
        int e = eidx[o0 + (act ? ii : 0)];
        int s = srcarr[e];
        float4 ea = *(const float4*)(esrc + (size_t)s * 8);
        float4 eb = *(const float4*)(esrc + (size_t)s * 8 + 4);
        float a[8] = {ea.x, ea.y, ea.z, ea.w, eb.x, eb.y, eb.z, eb.w};
        #pragma unroll
        for (int hh = 0; hh < 8; ++hh) {
            float v = act ? leakyf(a[hh] + ed[hh]) : -1e30f;
            #pragma unroll
            for (int o = 1; o < 64; o <<= 1) v = fmaxf(v, __shfl_xor(v, o));
            m[hh] = fmaxf(m[hh], v);
        }
    }
    // select this lane's head values (static-index binary tree)
    float mh, edh;
    {
        float t4a = (h & 4) ? m[4] : m[0];
        float t4b = (h & 4) ? m[5] : m[1];
        float t4c = (h & 4) ? m[6] : m[2];
        float t4d = (h & 4) ? m[7] : m[3];
        float t2a = (h & 2) ? t4c : t4a;
        float t2b = (h & 2) ? t4d : t4b;
        mh = (h & 1) ? t2b : t2a;
        float u4a = (h & 4) ? ed[4] : ed[0];
        float u4b = (h & 4) ? ed[5] : ed[1];
        float u4c = (h & 4) ? ed[6] : ed[2];
        float u4d = (h & 4) ? ed[7] : ed[3];
        float u2a = (h & 2) ? u4c : u4a;
        float u2b = (h & 2) ? u4d : u4b;
        edh = (h & 1) ? u2b : u2a;
    }
    // phase C: accumulate numerator / denominator; lane owns cols j0,j0+1
    float den = 0.f, num0 = 0.f, num1 = 0.f;
    for (int base = 0; base < deg; base += 64) {
        int ii = base + lane;
        bool act = ii < deg;
        int e = eidx[o0 + (act ? ii : 0)];
        int sreg = srcarr[e];
        int cl = deg - base;
        if (cl > 64) cl = 64;
        for (int i = 0; i < cl; ++i) {
            int s = __shfl(sreg, i);
            float ev = esrc[(size_t)s * 8 + h];
            float ex = __expf(leakyf(ev + edh) - mh);
            float2 xv = *(const float2*)(xs + (size_t)s * 128 + j0);
            num0 = fmaf(ex, xv.x, num0);
            num1 = fmaf(ex, xv.y, num1);
            den += ex;
        }
    }
    float inv = 1.f / (den + 1e-16f);
    float r0 = num0 * inv, r1 = num1 * inv;
    r0 = r0 > 0.f ? r0 : 0.f;
    r1 = r1 > 0.f ? r1 : 0.f;
    *(float2*)(outp + (size_t)n * 128 + j0) = make_float2(r0, r1);
}

// ---------------- semantic attention score: sum_n sum_j tanh((out@Wk)[j]+bk[j])*q[j] ----------------
__global__ __launch_bounds__(256) void score_kernel(
    const float* __restrict__ outk, const float* __restrict__ Wk,
    const float* __restrict__ bk, const float* __restrict__ q,
    float* __restrict__ scoreAcc, int N)
{
    __shared__ float lds[32 * 128];
    const int t = threadIdx.x;
    const int row0 = blockIdx.x * 32;
    #pragma unroll
    for (int p = 0; p < 4; ++p) {
        int idx = t + 256 * p;
        int r = idx >> 5;
        int c4 = idx & 31;
        float4 v = make_float4(0.f, 0.f, 0.f, 0.f);
        if (row0 + r < N) v = *(const float4*)(outk + (size_t)(row0 + r) * 128 + c4 * 4);
        *(float4*)(lds + r * 128 + c4 * 4) = v;
    }
    __syncthreads();
    const int rg = t >> 5, ct = t & 31;
    float acc[4][4];
    #pragma unroll
    for (int rr = 0; rr < 4; ++rr)
        #pragma unroll
        for (int c = 0; c < 4; ++c) acc[rr][c] = bk[ct + 32 * c];
    for (int i = 0; i < 128; i += 4) {
        float4 xv[4];
        #pragma unroll
        for (int rr = 0; rr < 4; ++rr) xv[rr] = *(const float4*)(lds + (rg + 8 * rr) * 128 + i);
        #pragma unroll
        for (int qq = 0; qq < 4; ++qq) {
            float wv[4];
            #pragma unroll
            for (int c = 0; c < 4; ++c) wv[c] = Wk[(size_t)(i + qq) * 128 + ct + 32 * c];
            #pragma unroll
            for (int rr = 0; rr < 4; ++rr) {
                float xs = ((const float*)&xv[rr])[qq];
                #pragma unroll
                for (int c = 0; c < 4; ++c) acc[rr][c] = fmaf(xs, wv[c], acc[rr][c]);
            }
        }
    }
    float qv[4];
    #pragma unroll
    for (int c = 0; c < 4; ++c) qv[c] = q[ct + 32 * c];
    float part = 0.f;
    #pragma unroll
    for (int rr = 0; rr < 4; ++rr) {
        int grow = row0 + rg + 8 * rr;
        float p_ = 0.f;
        #pragma unroll
        for (int c = 0; c < 4; ++c) p_ = fmaf(fast_tanh(acc[rr][c]), qv[c], p_);
        if (grow < N) part += p_;
    }
    #pragma unroll
    for (int o = 1; o < 32; o <<= 1) part += __shfl_xor(part, o, 32);
    if (ct == 0) atomicAdd(scoreAcc, part);
}

// ---------------- final: softmax(beta) blend + @W_lin + b_lin ----------------
__global__ __launch_bounds__(256) void final_kernel(
    const float* __restrict__ gg, const float* __restrict__ dg,
    const float* __restrict__ scoreAcc,
    const float* __restrict__ Wl, const float* __restrict__ bl,
    float* __restrict__ outp, int N, float invN)
{
    float s0 = scoreAcc[0] * invN, s1 = scoreAcc[1] * invN;
    float mx = fmaxf(s0, s1);
    float ee0 = __expf(s0 - mx), ee1 = __expf(s1 - mx);
    float bet0 = ee0 / (ee0 + ee1), bet1 = ee1 / (ee0 + ee1);
    __shared__ float lds[32 * 128];
    const int t = threadIdx.x;
    const int row0 = blockIdx.x * 32;
    #pragma unroll
    for (int p = 0; p < 4; ++p) {
        int idx = t + 256 * p;
        int r = idx >> 5;
        int c4 = idx & 31;
        float4 a = make_float4(0.f, 0.f, 0.f, 0.f), b = a, g;
        if (row0 + r < N) {
            a = *(const float4*)(gg + (size_t)(row0 + r) * 128 + c4 * 4);
            b = *(const float4*)(dg + (size_t)(row0 + r) * 128 + c4 * 4);
        }
        g.x = bet0 * a.x + bet1 * b.x;
        g.y = bet0 * a.y + bet1 * b.y;
        g.z = bet0 * a.z + bet1 * b.z;
        g.w = bet0 * a.w + bet1 * b.w;
        *(float4*)(lds + r * 128 + c4 * 4) = g;
    }
    __syncthreads();
    const int rg = t >> 5, ct = t & 31;
    float acc[4][2];
    #pragma unroll
    for (int rr = 0; rr < 4; ++rr)
        #pragma unroll
        for (int c = 0; c < 2; ++c) acc[rr][c] = bl[ct + 32 * c];
    for (int i = 0; i < 128; i += 4) {
        float4 xv[4];
        #pragma unroll
        for (int rr = 0; rr < 4; ++rr) xv[rr] = *(const float4*)(lds + (rg + 8 * rr) * 128 + i);
        #pragma unroll
        for (int qq = 0; qq < 4; ++qq) {
            float wv[2];
            #pragma unroll
            for (int c = 0; c < 2; ++c) wv[c] = Wl[(size_t)(i + qq) * 64 + ct + 32 * c];
            #pragma unroll
            for (int rr = 0; rr < 4; ++rr) {
                float xs = ((const float*)&xv[rr])[qq];
                #pragma unroll
                for (int c = 0; c < 2; ++c) acc[rr][c] = fmaf(xs, wv[c], acc[rr][c]);
            }
        }
    }
    #pragma unroll
    for (int rr = 0; rr < 4; ++rr) {
        int grow = row0 + rg + 8 * rr;
        if (grow < N) {
            #pragma unroll
            for (int c = 0; c < 2; ++c) outp[(size_t)grow * 64 + ct + 32 * c] = acc[rr][c];
        }
    }
}

extern "C" void kernel_launch(void* const* d_in, const int* in_sizes, int n_in,
                              void* d_out, int out_size, void* d_ws, size_t ws_size,
                              hipStream_t stream) {
    (void)n_in; (void)out_size; (void)ws_size;
    const float* x_gene = (const float*)d_in[0];
    const float* x_dis  = (const float*)d_in[1];
    const int* eg_src   = (const int*)d_in[2];
    const int* eg_dst   = (const int*)d_in[3];
    const int* edg_src  = (const int*)d_in[4];
    const int* edg_dst  = (const int*)d_in[5];
    const float* W_gene = (const float*)d_in[6];
    const float* b_gene = (const float*)d_in[7];
    const float* W_dis  = (const float*)d_in[8];
    const float* b_dis  = (const float*)d_in[9];
    const float* att_src_gg = (const float*)d_in[10];
    const float* att_dst_gg = (const float*)d_in[11];
    const float* att_src_dg = (const float*)d_in[12];
    const float* att_dst_dg = (const float*)d_in[13];
    const float* Wk    = (const float*)d_in[14];
    const float* bk    = (const float*)d_in[15];
    const float* q     = (const float*)d_in[16];
    const float* W_lin = (const float*)d_in[17];
    const float* b_lin = (const float*)d_in[18];
    float* out = (float*)d_out;

    const int NG_ = in_sizes[0] / 128;
    const int ND_ = in_sizes[1] / 128;
    const int EG_ = in_sizes[2];
    const int EDG_ = in_sizes[4];

    char* w = (char*)d_ws;
    auto alloc = [&](size_t bytes) -> char* {
        char* p = w;
        w += (bytes + 255) & ~(size_t)255;
        return p;
    };
    float* hg       = (float*)alloc((size_t)NG_ * 128 * 4);
    float* hd       = (float*)alloc((size_t)ND_ * 128 * 4);
    float* e_src_gg = (float*)alloc((size_t)NG_ * 8 * 4);
    float* e_dst_gg = (float*)alloc((size_t)NG_ * 8 * 4);
    float* e_dst_dg = (float*)alloc((size_t)NG_ * 8 * 4);
    float* e_src_dg = (float*)alloc((size_t)ND_ * 8 * 4);
    float* out_gg   = (float*)alloc((size_t)NG_ * 128 * 4);
    int* cnt   = (int*)alloc((size_t)(NG_ + 1) * 4);
    int* offg  = (int*)alloc((size_t)(NG_ + 1) * 4);
    int* offd  = (int*)alloc((size_t)(NG_ + 1) * 4);
    int* run   = (int*)alloc((size_t)NG_ * 4);
    int* eidx_g = (int*)alloc((size_t)EG_ * 4);
    int* eidx_d = (int*)alloc((size_t)EDG_ * 4);
    int* bsum  = (int*)alloc(8192);
    int* boff  = (int*)alloc(8192);
    float* score = (float*)alloc(256);
    float* out_dg = hg;  // hg is dead after the gg aggregation; alias to save 51 MB

    const int nb = (NG_ + 255) / 256;

    // 1. projections (+ e-vectors)
    proj_kernel<<<(NG_ + 31) / 32, 256, 0, stream>>>(
        x_gene, W_gene, b_gene, hg, NG_,
        att_src_gg, e_src_gg, att_dst_gg, e_dst_gg, att_dst_dg, e_dst_dg);
    proj_kernel<<<(ND_ + 31) / 32, 256, 0, stream>>>(
        x_dis, W_dis, b_dis, hd, ND_,
        att_src_dg, e_src_dg, (const float*)nullptr, (float*)nullptr,
        (const float*)nullptr, (float*)nullptr);

    // 2. CSR (gene-gene) + aggregate -> out_gg
    hipMemsetAsync(cnt, 0, (size_t)NG_ * 4, stream);
    hist_kernel<<<(EG_ + 255) / 256, 256, 0, stream>>>(eg_dst, EG_, cnt);
    scan_block_reduce<<<nb, 256, 0, stream>>>(cnt, NG_, bsum);
    scan_bsum<<<1, 1024, 0, stream>>>(bsum, nb, boff);
    scan_final<<<nb, 256, 0, stream>>>(cnt, NG_, boff, offg, EG_);
    hipMemcpyAsync(run, offg, (size_t)NG_ * 4, hipMemcpyDeviceToDevice, stream);
    scatter_kernel<<<(EG_ + 255) / 256, 256, 0, stream>>>(eg_dst, EG_, run, eidx_g);
    aggregate_kernel<<<(NG_ + 3) / 4, 256, 0, stream>>>(
        hg, e_src_gg, e_dst_gg, offg, eidx_g, eg_src, out_gg, NG_);

    // 3. CSR (disease-gene) + aggregate -> out_dg (aliases hg)
    hipMemsetAsync(cnt, 0, (size_t)NG_ * 4, stream);
    hist_kernel<<<(EDG_ + 255) / 256, 256, 0, stream>>>(edg_dst, EDG_, cnt);
    scan_block_reduce<<<nb, 256, 0, stream>>>(cnt, NG_, bsum);
    scan_bsum<<<1, 1024, 0, stream>>>(bsum, nb, boff);
    scan_final<<<nb, 256, 0, stream>>>(cnt, NG_, boff, offd, EDG_);
    hipMemcpyAsync(run, offd, (size_t)NG_ * 4, hipMemcpyDeviceToDevice, stream);
    scatter_kernel<<<(EDG_ + 255) / 256, 256, 0, stream>>>(edg_dst, EDG_, run, eidx_d);
    aggregate_kernel<<<(NG_ + 3) / 4, 256, 0, stream>>>(
        hd, e_src_dg, e_dst_dg, offd, eidx_d, edg_src, out_dg, NG_);

    // 4. semantic attention scores
    hipMemsetAsync(score, 0, 8, stream);
    score_kernel<<<(NG_ + 31) / 32, 256, 0, stream>>>(out_gg, Wk, bk, q, &score[0], NG_);
    score_kernel<<<(NG_ + 31) / 32, 256, 0, stream>>>(out_dg, Wk, bk, q, &score[1], NG_);

    // 5. blend + final linear
    final_kernel<<<(NG_ + 31) / 32, 256, 0, stream>>>(
        out_gg, out_dg, score, W_lin, b_lin, out, NG_, 1.0f / (float)NG_);
}